// Round 3
// baseline (673.851 us; speedup 1.0000x reference)
//
#include <hip/hip_runtime.h>
#include <math.h>

#define B_   8
#define C_   256
#define CI_  128
#define N_   4096
#define O3_  384

typedef unsigned short ushort_t;
typedef unsigned int uint_t;
typedef __attribute__((ext_vector_type(8))) short short8;
typedef __attribute__((ext_vector_type(16))) float floatx16;

// workspace layout (byte offsets)
#define OFF_W3   0ull          // fp32 [384][256]
#define OFF_B3   393216ull     // fp32 [384]
#define OFF_THT  394752ull     // bf16 [B][N][128]   (theta^T: q-major, c contig)
#define OFF_PHT  8783360ull    // bf16 [B][N][128]   (phi^T)
#define OFF_G16  17171968ull   // bf16 [B][128][N]   (g: c-major, n contig)
#define OFF_YT   25560576ull   // fp32 [B][128][N]-style [b][c][q] combined y
#define OFF_LP   42337792ull   // fp32 [2][B][N] l partials
#define OFF_YP   42599936ull   // fp32 [2][B][128][N] y partials (33.5 MB)
#define OFF_WY   42599936ull   // fp32 [B][256][N] — aliases YP (YP dead after combine)
// total ~76.2 MB

__device__ __forceinline__ ushort_t f2bf(float x) {
  union { float f; uint_t u; } c; c.f = x;
  return (ushort_t)((c.u + 0x7fffu + ((c.u >> 16) & 1u)) >> 16);
}
__device__ __forceinline__ uint_t pack_bf2(float a, float b) {
  union { float f; uint_t u; } x, y; x.f = a; y.f = b;
  uint_t lo = (x.u + 0x7fffu + ((x.u >> 16) & 1u)) >> 16;
  uint_t hi = (y.u + 0x7fffu + ((y.u >> 16) & 1u)) & 0xffff0000u;
  return lo | hi;
}
__device__ __forceinline__ void async_copy16(const void* g, void* l) {
  __builtin_amdgcn_global_load_lds(
      (const __attribute__((address_space(1))) unsigned int*)g,
      (__attribute__((address_space(3))) unsigned int*)l, 16, 0, 0);
}

__global__ __launch_bounds__(256) void pack_w(
    const float* __restrict__ g_w, const float* __restrict__ g_b,
    const float* __restrict__ th_w, const float* __restrict__ th_b,
    const float* __restrict__ ph_w, const float* __restrict__ ph_b,
    float* __restrict__ W3, float* __restrict__ b3)
{
  int i = blockIdx.x * 256 + threadIdx.x;
  int o = i >> 8;
  float v;
  if (o < 128)      v = g_w[i];
  else if (o < 256) v = th_w[i - 128*256];
  else              v = ph_w[i - 256*256];
  W3[i] = v;
  if ((i & 255) == 0)
    b3[o] = (o < 128) ? g_b[o] : (o < 256) ? th_b[o - 128] : ph_b[o - 256];
}

// Projection GEMM (fp32): routes to bf16 outputs in attn-ready layouts.
__global__ __launch_bounds__(256) void proj_gemm(
    const float* __restrict__ A, const float* __restrict__ bias,
    const float* __restrict__ X, ushort_t* __restrict__ tht,
    ushort_t* __restrict__ pht, ushort_t* __restrict__ g16)
{
  const int b  = blockIdx.z;
  const int o0 = blockIdx.y * 64;
  const int n0 = blockIdx.x * 64;
  const int tid = threadIdx.x;
  __shared__ float As[16 * 68];
  __shared__ float Xs[16 * 68];
  const int ty = tid >> 4, tx = tid & 15;
  float acc[4][4] = {};
  const float* Xb = X + (size_t)b * C_ * N_;

  const int lkA = tid & 15, loA = tid >> 4;
  const int lnX = tid & 63, lkX = tid >> 6;

  for (int k0 = 0; k0 < C_; k0 += 16) {
    #pragma unroll
    for (int r = 0; r < 4; ++r)
      As[lkA * 68 + loA + 16 * r] = A[(size_t)(o0 + loA + 16 * r) * C_ + k0 + lkA];
    #pragma unroll
    for (int r = 0; r < 4; ++r)
      Xs[(lkX + 4 * r) * 68 + lnX] = Xb[(size_t)(k0 + lkX + 4 * r) * N_ + n0 + lnX];
    __syncthreads();
    #pragma unroll
    for (int k = 0; k < 16; ++k) {
      float4 a4 = *(const float4*)&As[k * 68 + ty * 4];
      float4 x4 = *(const float4*)&Xs[k * 68 + tx * 4];
      float av[4] = {a4.x, a4.y, a4.z, a4.w};
      float xv[4] = {x4.x, x4.y, x4.z, x4.w};
      #pragma unroll
      for (int i = 0; i < 4; ++i)
        #pragma unroll
        for (int j = 0; j < 4; ++j)
          acc[i][j] += av[i] * xv[j];
    }
    __syncthreads();
  }
  #pragma unroll
  for (int i = 0; i < 4; ++i) {
    float bv = bias[o0 + ty * 4 + i];
    #pragma unroll
    for (int j = 0; j < 4; ++j) acc[i][j] += bv;
  }

  if (o0 < 128) {
    ushort_t* gp = g16 + (size_t)b * CI_ * N_;
    #pragma unroll
    for (int i = 0; i < 4; ++i) {
      ushort4 u = make_ushort4(f2bf(acc[i][0]), f2bf(acc[i][1]),
                               f2bf(acc[i][2]), f2bf(acc[i][3]));
      *(ushort4*)&gp[(size_t)(o0 + ty * 4 + i) * N_ + n0 + tx * 4] = u;
    }
  } else {
    ushort_t* tp = (o0 < 256) ? (tht + (size_t)b * N_ * CI_)
                              : (pht + (size_t)b * N_ * CI_);
    int ob = ((o0 < 256) ? (o0 - 128) : (o0 - 256)) + ty * 4;
    #pragma unroll
    for (int j = 0; j < 4; ++j) {
      ushort4 u = make_ushort4(f2bf(acc[0][j]), f2bf(acc[1][j]),
                               f2bf(acc[2][j]), f2bf(acc[3][j]));
      *(ushort4*)&tp[(size_t)(n0 + tx * 4 + j) * CI_ + ob] = u;
    }
  }
}

// ---------------------------------------------------------------------------
// MFMA flash attention, 32x32x16, transposed compute.
//   S^T[m][q] = phi[m][c] . theta^T[c][q]   (A = phi from LDS, B = theta regs)
//   p = exp(s - 20)  (constant shift: softmax-invariant; no running max)
//   y^T[c][q] += g[c][m] . P[m][q]          (A = g from LDS, B = P from LDS)
// Block: 128 threads = 2 waves; wave owns 64 q (2 q-tiles of 32).
// Grid: 512 = qb(32) x ms(2 key-split) x b(8); partials summed by combine().
// ---------------------------------------------------------------------------
#define LOG2E_  1.442695041f
#define MBIAS_  (-28.85390082f)   /* = -20 * log2(e) */

__global__ __launch_bounds__(128, 2) void attn_mfma(
    const ushort_t* __restrict__ tht, const ushort_t* __restrict__ pht,
    const ushort_t* __restrict__ g16, float* __restrict__ yp,
    float* __restrict__ lp)
{
  const int b  = blockIdx.x & 7;           // batch -> XCD
  const int ms = (blockIdx.x >> 3) & 1;    // key split
  const int qb = blockIdx.x >> 4;          // 0..31
  const int tid = threadIdx.x;
  const int w = tid >> 6;
  const int lane = tid & 63;
  const int l31 = lane & 31;
  const int h = lane >> 5;
  const int xk = l31 & 7;                  // XOR swizzle key

  __shared__ ushort_t phs[64 * 128];       // [m][c], chunk^(m&7)     16 KB
  __shared__ ushort_t gs [128 * 64];       // [c][m], chunk^(c&7)     16 KB
  __shared__ ushort_t Pl [2][64 * 64];     // per-wave [q][m], chunk^(q&7) 16 KB

  const int q0 = qb * 128 + w * 64;
  const int m_base = ms * 2048;

  const ushort_t* thb = tht + (size_t)b * N_ * CI_;
  const ushort_t* phb = pht + (size_t)b * N_ * CI_;
  const ushort_t* gbp = g16 + (size_t)b * CI_ * N_;

  // theta B-frags (lane: n=q fixed, k contiguous), register-resident
  short8 tf[2][8];
  #pragma unroll
  for (int qt = 0; qt < 2; ++qt)
    #pragma unroll
    for (int kk = 0; kk < 8; ++kk)
      tf[qt][kk] = *(const short8*)&thb[(size_t)(q0 + qt*32 + l31) * CI_ + kk*16 + h*8];

  floatx16 acc[2][4];
  #pragma unroll
  for (int qt = 0; qt < 2; ++qt)
    #pragma unroll
    for (int ct = 0; ct < 4; ++ct)
      #pragma unroll
      for (int r = 0; r < 16; ++r) acc[qt][ct][r] = 0.f;
  float lpart[2] = {0.f, 0.f};

  const int phr = lane >> 4, phu = lane & 15;   // phi staging coords
  const int gr  = lane >> 3, gu  = lane & 7;    // g staging coords

  for (int m0 = m_base; m0 < m_base + 2048; m0 += 64) {
    __syncthreads();   // prior iter's LDS readers done
    // stage phi [64 m][128 c] and g [128 c][64 m] via async DMA, XOR-swizzled
    #pragma unroll
    for (int i = 0; i < 8; ++i) {
      int row = w*32 + i*4 + phr;
      async_copy16(&phb[(size_t)(m0 + row) * CI_ + ((phu ^ (row & 7)) * 8)],
                   &phs[(w*32 + i*4) * 128]);
    }
    #pragma unroll
    for (int i = 0; i < 8; ++i) {
      int c = w*64 + i*8 + gr;
      async_copy16(&gbp[(size_t)c * N_ + m0 + ((gu ^ (c & 7)) * 8)],
                   &gs[(w*64 + i*8) * 64]);
    }
    __syncthreads();   // staging visible (vmcnt drained by barrier)

    // QK^T + softmax-exp + P pack, per m-tile
    #pragma unroll
    for (int mt = 0; mt < 2; ++mt) {
      floatx16 s0, s1;
      #pragma unroll
      for (int r = 0; r < 16; ++r) { s0[r] = 0.f; s1[r] = 0.f; }
      #pragma unroll
      for (int kk = 0; kk < 8; ++kk) {
        short8 pf = *(const short8*)&phs[(mt*32 + l31) * 128 + (((2*kk + h) ^ xk) * 8)];
        s0 = __builtin_amdgcn_mfma_f32_32x32x16_bf16(pf, tf[0][kk], s0, 0, 0, 0);
        s1 = __builtin_amdgcn_mfma_f32_32x32x16_bf16(pf, tf[1][kk], s1, 0, 0, 0);
      }
      // lane holds col q = qt*32+l31 (fixed), rows m = (r&3)+8*(r>>2)+4h + mt*32
      #pragma unroll
      for (int qt = 0; qt < 2; ++qt) {
        const floatx16& s = qt ? s1 : s0;
        float ls = 0.f;
        #pragma unroll
        for (int rq = 0; rq < 4; ++rq) {
          float p0 = exp2f(fmaf(s[4*rq+0], LOG2E_, MBIAS_));
          float p1 = exp2f(fmaf(s[4*rq+1], LOG2E_, MBIAS_));
          float p2 = exp2f(fmaf(s[4*rq+2], LOG2E_, MBIAS_));
          float p3 = exp2f(fmaf(s[4*rq+3], LOG2E_, MBIAS_));
          ls += (p0 + p1) + (p2 + p3);
          uint2 d = make_uint2(pack_bf2(p0, p1), pack_bf2(p2, p3));
          *(uint2*)&Pl[w][(qt*32 + l31) * 64 + (((mt*4 + rq) ^ xk) * 8) + h*4] = d;
        }
        lpart[qt] += ls;
      }
    }

    // PV: y^T[c][q] += g[c][m] * P[m][q]
    #pragma unroll
    for (int kk = 0; kk < 4; ++kk) {
      int pc = ((2*kk + h) ^ xk) * 8;
      short8 p0 = *(const short8*)&Pl[w][(l31) * 64 + pc];
      short8 p1 = *(const short8*)&Pl[w][(32 + l31) * 64 + pc];
      #pragma unroll
      for (int ct = 0; ct < 4; ++ct) {
        short8 gf = *(const short8*)&gs[(ct*32 + l31) * 64 + pc];
        acc[0][ct] = __builtin_amdgcn_mfma_f32_32x32x16_bf16(gf, p0, acc[0][ct], 0, 0, 0);
        acc[1][ct] = __builtin_amdgcn_mfma_f32_32x32x16_bf16(gf, p1, acc[1][ct], 0, 0, 0);
      }
    }
  }

  // epilogue: partial l (sum halves) + partial y stores
  float* ypb = yp + ((size_t)ms * 8 + b) * CI_ * N_;
  #pragma unroll
  for (int qt = 0; qt < 2; ++qt) {
    float lq = lpart[qt] + __shfl_xor(lpart[qt], 32);
    if (h == 0)
      lp[((size_t)ms * 8 + b) * N_ + q0 + qt*32 + l31] = lq;
    #pragma unroll
    for (int ct = 0; ct < 4; ++ct)
      #pragma unroll
      for (int r = 0; r < 16; ++r) {
        int c = ct*32 + (r&3) + 8*(r>>2) + 4*h;
        ypb[(size_t)c * N_ + q0 + qt*32 + l31] = acc[qt][ct][r];
      }
  }
}

// yt[b][c][q] = (yp0 + yp1) / (l0 + l1)
__global__ __launch_bounds__(256) void combine(
    const float* __restrict__ yp, const float* __restrict__ lp,
    float* __restrict__ yt)
{
  size_t i = ((size_t)blockIdx.x * 256 + threadIdx.x) * 4;
  int q = (int)(i & 4095);
  int b = (int)(i >> 19);
  const size_t half = (size_t)8 * CI_ * N_;
  float4 y0 = *(const float4*)&yp[i];
  float4 y1 = *(const float4*)&yp[half + i];
  float4 l0 = *(const float4*)&lp[(size_t)b * N_ + q];
  float4 l1 = *(const float4*)&lp[(size_t)8 * N_ + (size_t)b * N_ + q];
  float4 o;
  o.x = (y0.x + y1.x) / (l0.x + l1.x);
  o.y = (y0.y + y1.y) / (l0.y + l1.y);
  o.z = (y0.z + y1.z) / (l0.z + l1.z);
  o.w = (y0.w + y1.w) / (l0.w + l1.w);
  *(float4*)&yt[i] = o;
}

// W-conv GEMM (fp32): Out[b][o][n] = sum_k A[o][k] X[b][k][n] + bias[o]
__global__ __launch_bounds__(256) void gemm_bias(
    const float* __restrict__ A, const float* __restrict__ bias,
    const float* __restrict__ X, float* __restrict__ Out,
    int Odim, int Kdim)
{
  const int b  = blockIdx.z;
  const int o0 = blockIdx.y * 64;
  const int n0 = blockIdx.x * 64;
  const int tid = threadIdx.x;
  __shared__ float As[16 * 68];
  __shared__ float Xs[16 * 68];
  const int ty = tid >> 4, tx = tid & 15;
  float acc[4][4] = {};
  const float* Xb = X + (size_t)b * Kdim * N_;
  const int lkA = tid & 15, loA = tid >> 4;
  const int lnX = tid & 63, lkX = tid >> 6;

  for (int k0 = 0; k0 < Kdim; k0 += 16) {
    #pragma unroll
    for (int r = 0; r < 4; ++r)
      As[lkA * 68 + loA + 16 * r] = A[(size_t)(o0 + loA + 16 * r) * Kdim + k0 + lkA];
    #pragma unroll
    for (int r = 0; r < 4; ++r)
      Xs[(lkX + 4 * r) * 68 + lnX] = Xb[(size_t)(k0 + lkX + 4 * r) * N_ + n0 + lnX];
    __syncthreads();
    #pragma unroll
    for (int k = 0; k < 16; ++k) {
      float4 a4 = *(const float4*)&As[k * 68 + ty * 4];
      float4 x4 = *(const float4*)&Xs[k * 68 + tx * 4];
      float av[4] = {a4.x, a4.y, a4.z, a4.w};
      float xv[4] = {x4.x, x4.y, x4.z, x4.w};
      #pragma unroll
      for (int i = 0; i < 4; ++i)
        #pragma unroll
        for (int j = 0; j < 4; ++j)
          acc[i][j] += av[i] * xv[j];
    }
    __syncthreads();
  }
  #pragma unroll
  for (int i = 0; i < 4; ++i) {
    int o = o0 + ty * 4 + i;
    float bv = bias[o];
    float4 v = make_float4(acc[i][0] + bv, acc[i][1] + bv, acc[i][2] + bv, acc[i][3] + bv);
    *(float4*)&Out[((size_t)b * Odim + o) * N_ + n0 + tx * 4] = v;
  }
}

__global__ __launch_bounds__(256) void bn_stats(
    const float* __restrict__ WY, float* __restrict__ st)
{
  const int o = blockIdx.x;
  const int tid = threadIdx.x;
  float s = 0.f, s2 = 0.f;
  for (int b = 0; b < B_; ++b) {
    const float* p = WY + ((size_t)b * C_ + o) * N_;
    for (int n = tid * 4; n < N_; n += 256 * 4) {
      float4 v = *(const float4*)&p[n];
      s  += v.x + v.y + v.z + v.w;
      s2 += v.x * v.x + v.y * v.y + v.z * v.z + v.w * v.w;
    }
  }
  __shared__ float rs[256], rs2[256];
  rs[tid] = s; rs2[tid] = s2;
  __syncthreads();
  for (int off = 128; off > 0; off >>= 1) {
    if (tid < off) { rs[tid] += rs[tid + off]; rs2[tid] += rs2[tid + off]; }
    __syncthreads();
  }
  if (tid == 0) {
    const float M = (float)(B_ * N_);
    float mean = rs[0] / M;
    float var  = rs2[0] / M - mean * mean;
    st[o] = mean;
    st[256 + o] = rsqrtf(var + 1e-5f);
  }
}

__global__ __launch_bounds__(256) void bn_apply(
    const float* __restrict__ WY, const float* __restrict__ x,
    const float* __restrict__ st, const float* __restrict__ gamma,
    const float* __restrict__ beta, float* __restrict__ out)
{
  size_t i = ((size_t)blockIdx.x * 256 + threadIdx.x) * 4;
  int o = (int)((i >> 12) & 255);
  float4 w  = *(const float4*)&WY[i];
  float4 xv = *(const float4*)&x[i];
  float gsc = gamma[o] * st[256 + o];
  float bb  = beta[o] - st[o] * gsc;
  float4 v;
  v.x = w.x * gsc + bb + xv.x;
  v.y = w.y * gsc + bb + xv.y;
  v.z = w.z * gsc + bb + xv.z;
  v.w = w.w * gsc + bb + xv.w;
  *(float4*)&out[i] = v;
}

extern "C" void kernel_launch(void* const* d_in, const int* in_sizes, int n_in,
                              void* d_out, int out_size, void* d_ws, size_t ws_size,
                              hipStream_t stream)
{
  const float* x       = (const float*)d_in[0];
  const float* g_w     = (const float*)d_in[1];
  const float* g_b     = (const float*)d_in[2];
  const float* theta_w = (const float*)d_in[3];
  const float* theta_b = (const float*)d_in[4];
  const float* phi_w   = (const float*)d_in[5];
  const float* phi_b   = (const float*)d_in[6];
  const float* W_w     = (const float*)d_in[7];
  const float* W_b     = (const float*)d_in[8];
  const float* gamma   = (const float*)d_in[9];
  const float* beta    = (const float*)d_in[10];
  float* out = (float*)d_out;

  char* ws = (char*)d_ws;
  float*    W3  = (float*)(ws + OFF_W3);
  float*    b3  = (float*)(ws + OFF_B3);
  ushort_t* tht = (ushort_t*)(ws + OFF_THT);
  ushort_t* pht = (ushort_t*)(ws + OFF_PHT);
  ushort_t* g16 = (ushort_t*)(ws + OFF_G16);
  float*    yt  = (float*)(ws + OFF_YT);
  float*    lp  = (float*)(ws + OFF_LP);
  float*    ypp = (float*)(ws + OFF_YP);
  float*    WY  = (float*)(ws + OFF_WY);   // aliases ypp (disjoint lifetime)
  float*    ST  = b3 + 512;                // reuse tail of W3/b3 region? no — keep separate:
  static_assert(OFF_B3 + 1536 <= OFF_THT, "");
  // small stats buffer: put at end of lp region (lp uses 2*8*4096*4 = 262144 B)
  ST = (float*)(ws + OFF_LP + 262144 - 4096);  // 512 floats needed, 1024 spare bytes... use dedicated:
  ST = (float*)(ws + OFF_YP + (size_t)33554432);  // right after WY/YP union end

  pack_w<<<384, 256, 0, stream>>>(g_w, g_b, theta_w, theta_b, phi_w, phi_b, W3, b3);
  proj_gemm<<<dim3(64, 6, 8), 256, 0, stream>>>(W3, b3, x, tht, pht, g16);
  attn_mfma<<<512, 128, 0, stream>>>(tht, pht, g16, ypp, lp);
  combine<<<4096, 256, 0, stream>>>(ypp, lp, yt);
  gemm_bias<<<dim3(64, 4, 8), 256, 0, stream>>>(W_w, W_b, yt, WY, C_, CI_);
  bn_stats<<<256, 256, 0, stream>>>(WY, ST);
  bn_apply<<<8192, 256, 0, stream>>>(WY, x, ST, gamma, beta, out);
}

// Round 4
// 281.954 us; speedup vs baseline: 2.3899x; 2.3899x over previous
//
#include <hip/hip_runtime.h>
#include <math.h>

#define B_   8
#define C_   256
#define CI_  128
#define N_   4096

typedef unsigned short ushort_t;
typedef unsigned int uint_t;
typedef __attribute__((ext_vector_type(8))) short short8;
typedef __attribute__((ext_vector_type(16))) float floatx16;

// workspace layout (byte offsets)
#define OFF_W3B  0ull           // bf16 [384][256]
#define OFF_B3   196608ull      // fp32 [384]
#define OFF_XT   198144ull      // bf16 [B][N][256]  (x^T, c contig)      16.8 MB
#define OFF_THT  16975360ull    // bf16 [B][N][128]  theta^T              8.4 MB
#define OFF_PHT  25363968ull    // bf16 [B][N][128]  phi^T                8.4 MB
#define OFF_G16  33752576ull    // bf16 [B][128][N]  g (n contig)         8.4 MB
#define OFF_LP   42141184ull    // fp32 [2][B][N]    l partials
#define OFF_YP   42403328ull    // fp32 [2][B][128][N] y partials         33.6 MB
#define OFF_YT   75957760ull    // fp32 [B][128][N]  combined y           16.8 MB
#define OFF_WY   198144ull      // fp32 [B][256][N] — aliases XT+THT+PHT (dead by then)
#define OFF_ST   92735232ull    // fp32 [2][256]
// total ~92.7 MB

__device__ __forceinline__ ushort_t f2bf(float x) {
  union { float f; uint_t u; } c; c.f = x;
  return (ushort_t)((c.u + 0x7fffu + ((c.u >> 16) & 1u)) >> 16);
}
__device__ __forceinline__ uint_t pack_bf2(float a, float b) {
  union { float f; uint_t u; } x, y; x.f = a; y.f = b;
  uint_t lo = (x.u + 0x7fffu + ((x.u >> 16) & 1u)) >> 16;
  uint_t hi = (y.u + 0x7fffu + ((y.u >> 16) & 1u)) & 0xffff0000u;
  return lo | hi;
}
__device__ __forceinline__ void async_copy16(const void* g, void* l) {
  __builtin_amdgcn_global_load_lds(
      (const __attribute__((address_space(1))) unsigned int*)g,
      (__attribute__((address_space(3))) unsigned int*)l, 16, 0, 0);
}

// -------- pack weights: [g|theta|phi] -> bf16 [384][256] + fp32 bias[384] ----
__global__ __launch_bounds__(256) void pack_w(
    const float* __restrict__ g_w, const float* __restrict__ g_b,
    const float* __restrict__ th_w, const float* __restrict__ th_b,
    const float* __restrict__ ph_w, const float* __restrict__ ph_b,
    ushort_t* __restrict__ W3b, float* __restrict__ b3)
{
  int i = blockIdx.x * 256 + threadIdx.x;
  int o = i >> 8;
  float v;
  if (o < 128)      v = g_w[i];
  else if (o < 256) v = th_w[i - 128*256];
  else              v = ph_w[i - 256*256];
  W3b[i] = f2bf(v);
  if ((i & 255) == 0)
    b3[o] = (o < 128) ? g_b[o] : (o < 256) ? th_b[o - 128] : ph_b[o - 256];
}

// -------- x [b][c][n] fp32 -> xt [b][n][c] bf16 (64x64 LDS transpose tiles) --
__global__ __launch_bounds__(256) void xcast(
    const float* __restrict__ x, ushort_t* __restrict__ xt)
{
  const int b = blockIdx.z, c0 = blockIdx.y * 64, n0 = blockIdx.x * 64;
  const int tid = threadIdx.x;
  __shared__ float xs[64][65];
  const int nq = (tid & 15) * 4, cr = tid >> 4;
  #pragma unroll
  for (int i = 0; i < 4; ++i) {
    float4 v = *(const float4*)&x[((size_t)b * C_ + c0 + cr + 16*i) * N_ + n0 + nq];
    xs[cr + 16*i][nq] = v.x; xs[cr + 16*i][nq+1] = v.y;
    xs[cr + 16*i][nq+2] = v.z; xs[cr + 16*i][nq+3] = v.w;
  }
  __syncthreads();
  const int n = tid >> 2, cs = (tid & 3) * 16;
  uint_t u[8];
  #pragma unroll
  for (int j = 0; j < 8; ++j)
    u[j] = pack_bf2(xs[cs + 2*j][n], xs[cs + 2*j + 1][n]);
  ushort_t* dst = &xt[((size_t)b * N_ + n0 + n) * C_ + c0 + cs];
  *(uint4*)dst       = make_uint4(u[0], u[1], u[2], u[3]);
  *(uint4*)(dst + 8) = make_uint4(u[4], u[5], u[6], u[7]);
}

// -------- projection GEMM, bf16 MFMA 32x32x16 -------------------------------
// GMODE=0: C rows=o cols=n (A=W, B=xt) -> theta^T/phi^T [b][n][c] stores
// GMODE=1: C rows=n cols=o (A=xt, B=W) -> g [b][c][n] stores
template<int GMODE>
__global__ __launch_bounds__(256, 2) void proj_mfma(
    const ushort_t* __restrict__ W3b, const float* __restrict__ b3,
    const ushort_t* __restrict__ xt, ushort_t* __restrict__ tht,
    ushort_t* __restrict__ pht, ushort_t* __restrict__ g16)
{
  const int b = blockIdx.z, nb = blockIdx.x, ot = blockIdx.y;
  const int o0 = GMODE ? 0 : (128 + ot * 128);
  const int tid = threadIdx.x, w = tid >> 6, lane = tid & 63;
  const int l31 = lane & 31, h = lane >> 5, xk = l31 & 7;
  __shared__ ushort_t ws_l[128 * 64];
  __shared__ ushort_t xs_l[128 * 64];
  const ushort_t* xb = xt + (size_t)b * N_ * C_;
  const int n0 = nb * 128;
  floatx16 acc[4];
  #pragma unroll
  for (int ct = 0; ct < 4; ++ct)
    #pragma unroll
    for (int r = 0; r < 16; ++r) acc[ct][r] = 0.f;

  const int gr = lane >> 3, gu = lane & 7;
  for (int k0 = 0; k0 < C_; k0 += 64) {
    __syncthreads();
    #pragma unroll
    for (int i = 0; i < 4; ++i) {
      int r = w*32 + i*8 + gr;
      async_copy16(&W3b[(size_t)(o0 + r) * C_ + k0 + ((gu ^ (r & 7)) * 8)],
                   &ws_l[(w*32 + i*8) * 64]);
      async_copy16(&xb[(size_t)(n0 + r) * C_ + k0 + ((gu ^ (r & 7)) * 8)],
                   &xs_l[(w*32 + i*8) * 64]);
    }
    __syncthreads();
    #pragma unroll
    for (int kk = 0; kk < 4; ++kk) {
      int fc = ((2*kk + h) ^ xk) * 8;
      short8 bf = GMODE ? *(const short8*)&ws_l[(w*32 + l31) * 64 + fc]
                        : *(const short8*)&xs_l[(w*32 + l31) * 64 + fc];
      #pragma unroll
      for (int ct = 0; ct < 4; ++ct) {
        short8 af = GMODE ? *(const short8*)&xs_l[(ct*32 + l31) * 64 + fc]
                          : *(const short8*)&ws_l[(ct*32 + l31) * 64 + fc];
        acc[ct] = __builtin_amdgcn_mfma_f32_32x32x16_bf16(af, bf, acc[ct], 0, 0, 0);
      }
    }
  }

  if (GMODE) {
    float bv = b3[w*32 + l31];
    ushort_t* gp = g16 + ((size_t)b * CI_ + w*32 + l31) * N_;
    #pragma unroll
    for (int ct = 0; ct < 4; ++ct)
      #pragma unroll
      for (int rq = 0; rq < 4; ++rq) {
        uint2 d = make_uint2(pack_bf2(acc[ct][4*rq+0] + bv, acc[ct][4*rq+1] + bv),
                             pack_bf2(acc[ct][4*rq+2] + bv, acc[ct][4*rq+3] + bv));
        *(uint2*)&gp[n0 + ct*32 + 8*rq + 4*h] = d;
      }
  } else {
    ushort_t* tp = ((ot == 0) ? tht : pht) + ((size_t)b * N_ + n0 + w*32 + l31) * CI_;
    #pragma unroll
    for (int ct = 0; ct < 4; ++ct)
      #pragma unroll
      for (int rq = 0; rq < 4; ++rq) {
        float4 bv = *(const float4*)&b3[o0 + ct*32 + 8*rq + 4*h];
        uint2 d = make_uint2(pack_bf2(acc[ct][4*rq+0] + bv.x, acc[ct][4*rq+1] + bv.y),
                             pack_bf2(acc[ct][4*rq+2] + bv.z, acc[ct][4*rq+3] + bv.w));
        *(uint2*)&tp[ct*32 + 8*rq + 4*h] = d;
      }
  }
}

// -------- MFMA flash attention, 32x32x16, 1 q-tile/wave, 4 waves/block ------
#define LOG2E_  1.442695041f
#define MBIAS_  (-28.85390082f)   /* = -20 * log2(e) */

__global__ __launch_bounds__(256, 2) void attn_mfma(
    const ushort_t* __restrict__ tht, const ushort_t* __restrict__ pht,
    const ushort_t* __restrict__ g16, float* __restrict__ yp,
    float* __restrict__ lp)
{
  const int b  = blockIdx.x & 7;           // batch -> XCD
  const int ms = (blockIdx.x >> 3) & 1;    // key split
  const int qb = blockIdx.x >> 4;          // 0..31
  const int tid = threadIdx.x, w = tid >> 6, lane = tid & 63;
  const int l31 = lane & 31, h = lane >> 5, xk = l31 & 7;

  __shared__ ushort_t phs[64 * 128];       // [m][c]  16 KB
  __shared__ ushort_t gs [128 * 64];       // [c][m]  16 KB
  __shared__ ushort_t Pl [4][32 * 64];     // per-wave [q][m] 16 KB

  const int q0w = qb * 128 + w * 32;
  const int m_base = ms * 2048;

  const ushort_t* thb = tht + (size_t)b * N_ * CI_;
  const ushort_t* phb = pht + (size_t)b * N_ * CI_;
  const ushort_t* gbp = g16 + (size_t)b * CI_ * N_;

  // theta B-frags (lane: col q = l31, k contig), register-resident
  short8 tf[8];
  #pragma unroll
  for (int kk = 0; kk < 8; ++kk)
    tf[kk] = *(const short8*)&thb[(size_t)(q0w + l31) * CI_ + kk*16 + h*8];

  floatx16 acc[4];
  #pragma unroll
  for (int ct = 0; ct < 4; ++ct)
    #pragma unroll
    for (int r = 0; r < 16; ++r) acc[ct][r] = 0.f;
  float lpart = 0.f;

  const int phr = lane >> 4, phu = lane & 15;
  const int gr  = lane >> 3, gu  = lane & 7;

  for (int m0 = m_base; m0 < m_base + 2048; m0 += 64) {
    __syncthreads();   // prior iter's LDS readers done
    #pragma unroll
    for (int i = 0; i < 4; ++i) {
      int row = w*16 + i*4 + phr;
      async_copy16(&phb[(size_t)(m0 + row) * CI_ + ((phu ^ (row & 7)) * 8)],
                   &phs[(w*16 + i*4) * 128]);
    }
    #pragma unroll
    for (int i = 0; i < 4; ++i) {
      int c = w*32 + i*8 + gr;
      async_copy16(&gbp[(size_t)c * N_ + m0 + ((gu ^ (c & 7)) * 8)],
                   &gs[(w*32 + i*8) * 64]);
    }
    __syncthreads();   // staging visible

    // QK^T + exp + P pack (lane: col q fixed -> all softmax math lane-local)
    #pragma unroll
    for (int mt = 0; mt < 2; ++mt) {
      floatx16 s;
      #pragma unroll
      for (int r = 0; r < 16; ++r) s[r] = 0.f;
      #pragma unroll
      for (int kk = 0; kk < 8; ++kk) {
        short8 pf = *(const short8*)&phs[(mt*32 + l31) * 128 + (((2*kk + h) ^ xk) * 8)];
        s = __builtin_amdgcn_mfma_f32_32x32x16_bf16(pf, tf[kk], s, 0, 0, 0);
      }
      float ls = 0.f;
      #pragma unroll
      for (int rq = 0; rq < 4; ++rq) {
        float p0 = exp2f(fmaf(s[4*rq+0], LOG2E_, MBIAS_));
        float p1 = exp2f(fmaf(s[4*rq+1], LOG2E_, MBIAS_));
        float p2 = exp2f(fmaf(s[4*rq+2], LOG2E_, MBIAS_));
        float p3 = exp2f(fmaf(s[4*rq+3], LOG2E_, MBIAS_));
        ls += (p0 + p1) + (p2 + p3);
        uint2 d = make_uint2(pack_bf2(p0, p1), pack_bf2(p2, p3));
        *(uint2*)&Pl[w][l31 * 64 + (((mt*4 + rq) ^ xk) * 8) + h*4] = d;
      }
      lpart += ls;
    }

    // PV: y^T[c][q] += g[c][m] . P[m][q]  (same-wave DS ordering covers P)
    #pragma unroll
    for (int kk = 0; kk < 4; ++kk) {
      int pc = ((2*kk + h) ^ xk) * 8;
      short8 pfr = *(const short8*)&Pl[w][l31 * 64 + pc];
      #pragma unroll
      for (int ct = 0; ct < 4; ++ct) {
        short8 gf = *(const short8*)&gs[(ct*32 + l31) * 64 + pc];
        acc[ct] = __builtin_amdgcn_mfma_f32_32x32x16_bf16(gf, pfr, acc[ct], 0, 0, 0);
      }
    }
  }

  // epilogue: partial l + partial y
  float lq = lpart + __shfl_xor(lpart, 32);
  if (h == 0)
    lp[((size_t)ms * 8 + b) * N_ + q0w + l31] = lq;
  float* ypb = yp + ((size_t)ms * 8 + b) * CI_ * N_;
  #pragma unroll
  for (int ct = 0; ct < 4; ++ct)
    #pragma unroll
    for (int r = 0; r < 16; ++r) {
      int c = ct*32 + (r & 3) + 8*(r >> 2) + 4*h;
      ypb[(size_t)c * N_ + q0w + l31] = acc[ct][r];
    }
}

// -------- combine: yt[b][c][q] = (yp0 + yp1) / (l0 + l1) --------------------
__global__ __launch_bounds__(256) void combine(
    const float* __restrict__ yp, const float* __restrict__ lp,
    float* __restrict__ yt)
{
  size_t i = ((size_t)blockIdx.x * 256 + threadIdx.x) * 4;
  int q = (int)(i & 4095);
  int b = (int)(i >> 19);
  const size_t half = (size_t)8 * CI_ * N_;
  float4 y0 = *(const float4*)&yp[i];
  float4 y1 = *(const float4*)&yp[half + i];
  float4 l0 = *(const float4*)&lp[(size_t)b * N_ + q];
  float4 l1 = *(const float4*)&lp[(size_t)8 * N_ + (size_t)b * N_ + q];
  float4 o;
  o.x = (y0.x + y1.x) / (l0.x + l1.x);
  o.y = (y0.y + y1.y) / (l0.y + l1.y);
  o.z = (y0.z + y1.z) / (l0.z + l1.z);
  o.w = (y0.w + y1.w) / (l0.w + l1.w);
  *(float4*)&yt[i] = o;
}

// -------- W-conv GEMM (fp32): Out[b][o][n] = sum_k A[o][k] X[b][k][n] + bias -
__global__ __launch_bounds__(256) void gemm_bias(
    const float* __restrict__ A, const float* __restrict__ bias,
    const float* __restrict__ X, float* __restrict__ Out,
    int Odim, int Kdim)
{
  const int b  = blockIdx.z;
  const int o0 = blockIdx.y * 64;
  const int n0 = blockIdx.x * 64;
  const int tid = threadIdx.x;
  __shared__ float As[16 * 68];
  __shared__ float Xs[16 * 68];
  const int ty = tid >> 4, tx = tid & 15;
  float acc[4][4] = {};
  const float* Xb = X + (size_t)b * Kdim * N_;
  const int lkA = tid & 15, loA = tid >> 4;
  const int lnX = tid & 63, lkX = tid >> 6;

  for (int k0 = 0; k0 < Kdim; k0 += 16) {
    #pragma unroll
    for (int r = 0; r < 4; ++r)
      As[lkA * 68 + loA + 16 * r] = A[(size_t)(o0 + loA + 16 * r) * Kdim + k0 + lkA];
    #pragma unroll
    for (int r = 0; r < 4; ++r)
      Xs[(lkX + 4 * r) * 68 + lnX] = Xb[(size_t)(k0 + lkX + 4 * r) * N_ + n0 + lnX];
    __syncthreads();
    #pragma unroll
    for (int k = 0; k < 16; ++k) {
      float4 a4 = *(const float4*)&As[k * 68 + ty * 4];
      float4 x4 = *(const float4*)&Xs[k * 68 + tx * 4];
      float av[4] = {a4.x, a4.y, a4.z, a4.w};
      float xv[4] = {x4.x, x4.y, x4.z, x4.w};
      #pragma unroll
      for (int i = 0; i < 4; ++i)
        #pragma unroll
        for (int j = 0; j < 4; ++j)
          acc[i][j] += av[i] * xv[j];
    }
    __syncthreads();
  }
  #pragma unroll
  for (int i = 0; i < 4; ++i) {
    int o = o0 + ty * 4 + i;
    float bv = bias[o];
    float4 v = make_float4(acc[i][0] + bv, acc[i][1] + bv, acc[i][2] + bv, acc[i][3] + bv);
    *(float4*)&Out[((size_t)b * Odim + o) * N_ + n0 + tx * 4] = v;
  }
}

__global__ __launch_bounds__(256) void bn_stats(
    const float* __restrict__ WY, float* __restrict__ st)
{
  const int o = blockIdx.x;
  const int tid = threadIdx.x;
  float s = 0.f, s2 = 0.f;
  for (int b = 0; b < B_; ++b) {
    const float* p = WY + ((size_t)b * C_ + o) * N_;
    for (int n = tid * 4; n < N_; n += 256 * 4) {
      float4 v = *(const float4*)&p[n];
      s  += v.x + v.y + v.z + v.w;
      s2 += v.x * v.x + v.y * v.y + v.z * v.z + v.w * v.w;
    }
  }
  __shared__ float rs[256], rs2[256];
  rs[tid] = s; rs2[tid] = s2;
  __syncthreads();
  for (int off = 128; off > 0; off >>= 1) {
    if (tid < off) { rs[tid] += rs[tid + off]; rs2[tid] += rs2[tid + off]; }
    __syncthreads();
  }
  if (tid == 0) {
    const float M = (float)(B_ * N_);
    float mean = rs[0] / M;
    float var  = rs2[0] / M - mean * mean;
    st[o] = mean;
    st[256 + o] = rsqrtf(var + 1e-5f);
  }
}

__global__ __launch_bounds__(256) void bn_apply(
    const float* __restrict__ WY, const float* __restrict__ x,
    const float* __restrict__ st, const float* __restrict__ gamma,
    const float* __restrict__ beta, float* __restrict__ out)
{
  size_t i = ((size_t)blockIdx.x * 256 + threadIdx.x) * 4;
  int o = (int)((i >> 12) & 255);
  float4 w  = *(const float4*)&WY[i];
  float4 xv = *(const float4*)&x[i];
  float gsc = gamma[o] * st[256 + o];
  float bb  = beta[o] - st[o] * gsc;
  float4 v;
  v.x = w.x * gsc + bb + xv.x;
  v.y = w.y * gsc + bb + xv.y;
  v.z = w.z * gsc + bb + xv.z;
  v.w = w.w * gsc + bb + xv.w;
  *(float4*)&out[i] = v;
}

extern "C" void kernel_launch(void* const* d_in, const int* in_sizes, int n_in,
                              void* d_out, int out_size, void* d_ws, size_t ws_size,
                              hipStream_t stream)
{
  const float* x       = (const float*)d_in[0];
  const float* g_w     = (const float*)d_in[1];
  const float* g_b     = (const float*)d_in[2];
  const float* theta_w = (const float*)d_in[3];
  const float* theta_b = (const float*)d_in[4];
  const float* phi_w   = (const float*)d_in[5];
  const float* phi_b   = (const float*)d_in[6];
  const float* W_w     = (const float*)d_in[7];
  const float* W_b     = (const float*)d_in[8];
  const float* gamma   = (const float*)d_in[9];
  const float* beta    = (const float*)d_in[10];
  float* out = (float*)d_out;

  char* ws = (char*)d_ws;
  ushort_t* W3b = (ushort_t*)(ws + OFF_W3B);
  float*    b3  = (float*)(ws + OFF_B3);
  ushort_t* xt  = (ushort_t*)(ws + OFF_XT);
  ushort_t* tht = (ushort_t*)(ws + OFF_THT);
  ushort_t* pht = (ushort_t*)(ws + OFF_PHT);
  ushort_t* g16 = (ushort_t*)(ws + OFF_G16);
  float*    lpp = (float*)(ws + OFF_LP);
  float*    ypp = (float*)(ws + OFF_YP);
  float*    yt  = (float*)(ws + OFF_YT);
  float*    WY  = (float*)(ws + OFF_WY);   // aliases XT/THT/PHT (dead by wgemm)
  float*    ST  = (float*)(ws + OFF_ST);

  pack_w<<<384, 256, 0, stream>>>(g_w, g_b, theta_w, theta_b, phi_w, phi_b, W3b, b3);
  xcast<<<dim3(64, 4, 8), 256, 0, stream>>>(x, xt);
  proj_mfma<0><<<dim3(32, 2, 8), 256, 0, stream>>>(W3b, b3, xt, tht, pht, g16);
  proj_mfma<1><<<dim3(32, 1, 8), 256, 0, stream>>>(W3b, b3, xt, tht, pht, g16);
  attn_mfma<<<512, 256, 0, stream>>>(tht, pht, g16, ypp, lpp);
  combine<<<4096, 256, 0, stream>>>(ypp, lpp, yt);
  gemm_bias<<<dim3(64, 4, 8), 256, 0, stream>>>(W_w, W_b, yt, WY, C_, CI_);
  bn_stats<<<256, 256, 0, stream>>>(WY, ST);
  bn_apply<<<8192, 256, 0, stream>>>(WY, x, ST, gamma, beta, out);
}